// Round 5
// baseline (46.982 us; speedup 1.0000x reference)
//
#include <hip/hip_runtime.h>
#include <math.h>

#define SRf 48000.0f
#define CSOUND 343.0f
#define RIR_LEN 24000
#define TAPS 81
#define HALFT 40
#define NB 8
#define NM 21                 // per-axis entries with order <= 10
#define NTRIP (NM * NM * NM)  // 9261 candidate triples
#define TILE 125
#define NT (RIR_LEN / TILE)   // 192 tiles per batch
#define BLOCK 256
#define CAP 256               // per-(batch,tile) bucket capacity

// 0.9^q for q = 0..10
__device__ __constant__ float c_beta[11] = {
    1.0f, 0.9f, 0.81f, 0.729f, 0.6561f, 0.59049f, 0.531441f,
    0.4782969f, 0.43046721f, 0.387420489f, 0.3486784401f};

// Per-axis image table restricted to order <= 10:
//   m in [0,10]:  p=0, n=m-5  -> sign=+1, off=2n, order=2|n|
//   m in [11,20]: p=1, n=m-15 -> sign=-1, off=2n, order=|n-1|+|n|
__device__ __forceinline__ void axis_entry(int m, float& sgn, float& off, int& ord) {
    if (m < 11) {
        int n = m - 5;
        sgn = 1.0f;
        off = 2.0f * (float)n;
        ord = 2 * abs(n);
    } else {
        int n = m - 15;
        sgn = -1.0f;
        off = 2.0f * (float)n;
        ord = abs(n - 1) + abs(n);
    }
}

// kernel 0: zero the bucket counters (6 KB) + compute the 8 origin outputs.
// (hipMemsetAsync's fillBuffer dispatch costs ~39us in-graph; this costs ~2us.)
__global__ __launch_bounds__(BLOCK) void k_zero(const float* __restrict__ x,
                                                int* __restrict__ cnt,
                                                float* __restrict__ out) {
    int t = blockIdx.x * BLOCK + threadIdx.x;
    if (t < NB * NT) cnt[t] = 0;
    if (t < NB) {
        const float* xb = x + t * 9;
        float r0 = xb[0] * 10.0f, r1 = xb[1] * 10.0f, r2 = xb[2] * 10.0f;
        float d0 = (xb[3] - xb[6]) * r0;
        float d1 = (xb[4] - xb[7]) * r1;
        float d2 = (xb[5] - xb[8]) * r2;
        float dist = sqrtf(d0 * d0 + d1 * d1 + d2 * d2);
        out[NB * RIR_LEN + t] = 40.0f + SRf * dist / CSOUND;
    }
}

// kernel 1: evaluate each candidate exactly once; append full params
// {amp, frac, sin(pi*frac), i0} to every tile bucket its window touches.
__global__ __launch_bounds__(BLOCK) void k_scan(const float* __restrict__ x,
                                                int* __restrict__ cnt,
                                                float4* __restrict__ lists) {
    const float PIF = 3.14159265358979323846f;
    int t = blockIdx.x * BLOCK + threadIdx.x;
    if (t >= NB * NTRIP) return;
    int b = t / NTRIP;
    int r = t - b * NTRIP;
    int mi = r / (NM * NM);
    int rem = r - mi * (NM * NM);
    int mj = rem / NM;
    int mk = rem - mj * NM;

    float si, oi_; int qi; axis_entry(mi, si, oi_, qi);
    float sj, oj_; int qj; axis_entry(mj, sj, oj_, qj);
    float sk, ok_; int qk; axis_entry(mk, sk, ok_, qk);
    int q = qi + qj + qk;
    if (q > 10) return;

    const float* xb = x + b * 9;
    float r0 = xb[0] * 10.0f, r1 = xb[1] * 10.0f, r2 = xb[2] * 10.0f;
    float dx = si * (xb[6] * r0) + oi_ * r0 - xb[3] * r0;
    float dy = sj * (xb[7] * r1) + oj_ * r1 - xb[4] * r1;
    float dz = sk * (xb[8] * r2) + ok_ * r2 - xb[5] * r2;
    float dist = sqrtf(dx * dx + dy * dy + dz * dz);

    float tau = SRf * dist / CSOUND;
    float i0f = floorf(tau);
    int i0 = (int)i0f;
    int lo = i0 + HALFT;
    if (lo >= RIR_LEN) return;
    int hi = min(i0 + HALFT + TAPS - 1, RIR_LEN - 1);

    float fr = tau - i0f;
    float4 e;
    e.x = c_beta[q] / (4.0f * PIF * dist);
    e.y = fr;
    e.z = __sinf(PIF * fr);
    e.w = __int_as_float(i0);

    int ta = lo / TILE, tb = hi / TILE;
    for (int tl = ta; tl <= tb; ++tl) {
        int bucket = b * NT + tl;
        int slot = atomicAdd(&cnt[bucket], 1);
        if (slot < CAP) lists[(size_t)bucket * CAP + slot] = e;
    }
}

// kernel 2: one block per (batch, tile); stage bucket to LDS, tap loop, writeout.
__global__ __launch_bounds__(BLOCK) void k_accum(const int* __restrict__ cnt,
                                                 const float4* __restrict__ lists,
                                                 float* __restrict__ out) {
    __shared__ float s_tile[TILE];
    __shared__ float4 s_e[CAP];

    const float PIF = 3.14159265358979323846f;
    const int wg = blockIdx.x;
    const int b = wg / NT;
    const int tile = wg - b * NT;
    const int t0 = tile * TILE;
    const int tid = threadIdx.x;

    for (int j = tid; j < TILE; j += BLOCK) s_tile[j] = 0.0f;
    int n = min(cnt[wg], CAP);
    for (int i = tid; i < n; i += BLOCK) s_e[i] = lists[(size_t)wg * CAP + i];
    __syncthreads();

    int total = n * TAPS;
    for (int w = tid; w < total; w += BLOCK) {
        int img = w / TAPS;
        int ki = w - img * TAPS;
        float4 e = s_e[img];
        int idx = __float_as_int(e.w) + HALFT + ki;
        if (idx < t0 || idx >= t0 + TILE) continue;

        float tt = (float)(ki - HALFT) - e.y;
        if (fabsf(tt) > (float)HALFT) continue;

        float win = 0.5f * (1.0f + __cosf(PIF * tt * (1.0f / 41.0f)));
        float snc = (tt == 0.0f) ? 1.0f
                                 : ((ki & 1) ? e.z : -e.z) * __builtin_amdgcn_rcpf(PIF * tt);
        atomicAdd(&s_tile[idx - t0], e.x * snc * win);
    }
    __syncthreads();

    for (int j = tid; j < TILE; j += BLOCK) out[b * RIR_LEN + t0 + j] = s_tile[j];
}

extern "C" void kernel_launch(void* const* d_in, const int* in_sizes, int n_in,
                              void* d_out, int out_size, void* d_ws, size_t ws_size,
                              hipStream_t stream) {
    const float* x = (const float*)d_in[0];
    float* out = (float*)d_out;

    int* cnt = (int*)d_ws;                                   // 1536 ints = 6 KB
    float4* lists = (float4*)((char*)d_ws + (size_t)NB * NT * sizeof(int));  // 6.3 MB

    k_zero<<<(NB * NT + BLOCK - 1) / BLOCK, BLOCK, 0, stream>>>(x, cnt, out);
    k_scan<<<(NB * NTRIP + BLOCK - 1) / BLOCK, BLOCK, 0, stream>>>(x, cnt, lists);
    k_accum<<<NB * NT, BLOCK, 0, stream>>>(cnt, lists, out);
}